// Round 1
// baseline (531.059 us; speedup 1.0000x reference)
//
#include <hip/hip_runtime.h>

#define K_CODES 1024
#define D_DIM   256
#define N_VEC   32768
#define BETA    0.25f
#define DECAY   0.99f
#define EPSV    1e-5f

// d_out layout (float32), offsets in elements
#define OFF_ZQ   0
#define OFF_IDX  8388608
#define OFF_LOSS 8421376
#define OFF_EMB  8421377
#define OFF_CS   8683521
#define OFF_EMAW 8684545

#define BM 16   // n-vectors per block
#define BD 8    // d-chunk for embedding LDS tile

// ---------------------------------------------------------------- init
__global__ void k_init(float* __restrict__ out) {
    int i = blockIdx.x * 256 + threadIdx.x;   // grid 1024*256 = 262144
    if (i == 0) out[OFF_LOSS] = 0.f;
    if (i < K_CODES) out[OFF_CS + i] = 0.f;
    if (i < K_CODES * D_DIM) out[OFF_EMAW + i] = 0.f;
}

// ---------------------------------------------------------------- ||e||^2
__global__ void k_enorm(const float* __restrict__ emb, float* __restrict__ out) {
    int row  = blockIdx.x * 4 + (threadIdx.x >> 6);   // 256 blocks * 4 rows
    int lane = threadIdx.x & 63;
    float4 v = reinterpret_cast<const float4*>(emb + row * D_DIM)[lane];
    float s = v.x * v.x + v.y * v.y + v.z * v.z + v.w * v.w;
    #pragma unroll
    for (int o = 32; o > 0; o >>= 1) s += __shfl_xor(s, o, 64);
    if (lane == 0) out[OFF_EMB + row] = s;   // scratch; K3 overwrites region
}

// ---------------------------------------------------------------- main
__global__ __launch_bounds__(256, 2)
void k_main(const float* __restrict__ z, const float* __restrict__ emb,
            float* __restrict__ out) {
    __shared__ float ztr[D_DIM][BM];        // z tile transposed: [d][n] 16 KB
    __shared__ float et[K_CODES][BD + 1];   // stride 9 (odd) -> conflict-free
    __shared__ float enorm_s[K_CODES];
    __shared__ float znorm_s[BM];
    __shared__ float psum[16][17];
    __shared__ int   js_s[BM];
    __shared__ float dmin_s[BM];

    const int tid = threadIdx.x;
    const int n0  = blockIdx.x * BM;        // 2048 blocks
    const int b   = n0 >> 10;
    const int hw0 = n0 & 1023;              // multiple of 16
    const float* zb = z + b * (D_DIM * 1024) + hw0;

    // ---- stage z tile (coalesced float4 along n), transposed into LDS
    #pragma unroll
    for (int rep = 0; rep < 4; ++rep) {
        int flat = rep * 256 + tid;         // 0..1023
        int d    = flat >> 2;
        int n4   = (flat & 3) * 4;
        float4 v = *reinterpret_cast<const float4*>(zb + d * 1024 + n4);
        *reinterpret_cast<float4*>(&ztr[d][n4]) = v;
    }
    // ---- stage ||e||^2
    #pragma unroll
    for (int rep = 0; rep < 4; ++rep) {
        int j = rep * 256 + tid;
        enorm_s[j] = out[OFF_EMB + j];
    }
    __syncthreads();

    // ---- ||z||^2 per n (partial per 16-d segment, then reduce)
    {
        int nn = tid & 15, seg = tid >> 4;
        float s = 0.f;
        #pragma unroll
        for (int d2 = 0; d2 < 16; ++d2) {
            float v = ztr[seg * 16 + d2][nn];
            s += v * v;
        }
        psum[seg][nn] = s;
    }
    __syncthreads();
    if (tid < BM) {
        float s = 0.f;
        #pragma unroll
        for (int seg = 0; seg < 16; ++seg) s += psum[seg][tid];
        znorm_s[tid] = s;
    }

    const int tj = tid & 63;
    const int tn = tid >> 6;   // wave id: owns n = tn*4 .. tn*4+3

    float acc[4][16];
    #pragma unroll
    for (int a = 0; a < 4; ++a)
        #pragma unroll
        for (int c = 0; c < 16; ++c) acc[a][c] = 0.f;

    // ---- dot-product main loop over d-chunks
    for (int dt = 0; dt < D_DIM / BD; ++dt) {
        __syncthreads();                     // protect et reuse
        #pragma unroll
        for (int rep = 0; rep < 8; ++rep) {  // 1024 x 8 floats
            int flat = rep * 256 + tid;      // 0..2047
            int j    = flat >> 1;
            int dq   = (flat & 1) * 4;
            float4 v = *reinterpret_cast<const float4*>(emb + j * D_DIM + dt * BD + dq);
            et[j][dq + 0] = v.x; et[j][dq + 1] = v.y;
            et[j][dq + 2] = v.z; et[j][dq + 3] = v.w;
        }
        __syncthreads();
        #pragma unroll
        for (int dd = 0; dd < BD; ++dd) {
            int d = dt * BD + dd;
            float zv0 = ztr[d][tn * 4 + 0];
            float zv1 = ztr[d][tn * 4 + 1];
            float zv2 = ztr[d][tn * 4 + 2];
            float zv3 = ztr[d][tn * 4 + 3];
            #pragma unroll
            for (int jj = 0; jj < 16; ++jj) {
                float ev = et[jj * 64 + tj][dd];   // lane-stride 9 words: no conflict
                acc[0][jj] += zv0 * ev;
                acc[1][jj] += zv1 * ev;
                acc[2][jj] += zv2 * ev;
                acc[3][jj] += zv3 * ev;
            }
        }
    }
    __syncthreads();

    // ---- finalize distances + argmin (tie -> smaller j, as np.argmin)
    const int wn0 = tn * 4;
    #pragma unroll
    for (int nn = 0; nn < 4; ++nn) {
        float zn = znorm_s[wn0 + nn];
        float best = 3.4e38f; int bestj = 0;
        #pragma unroll
        for (int jj = 0; jj < 16; ++jj) {
            int j = jj * 64 + tj;            // ascending j within thread
            float dist = zn + enorm_s[j] - 2.f * acc[nn][jj];
            if (dist < best || (dist == best && j < bestj)) { best = dist; bestj = j; }
        }
        #pragma unroll
        for (int o = 1; o < 64; o <<= 1) {
            float ov = __shfl_xor(best, o, 64);
            int   oj = __shfl_xor(bestj, o, 64);
            if (ov < best || (ov == best && oj < bestj)) { best = ov; bestj = oj; }
        }
        if (tj == 0) {
            int n = n0 + wn0 + nn;
            out[OFF_IDX + n] = (float)bestj;
            js_s[wn0 + nn]   = bestj;
            dmin_s[wn0 + nn] = best;
            atomicAdd(out + OFF_CS + bestj, 1.0f);
        }
    }
    if (tj == 0) {
        float s = dmin_s[wn0] + dmin_s[wn0 + 1] + dmin_s[wn0 + 2] + dmin_s[wn0 + 3];
        atomicAdd(out + OFF_LOSS, s);        // sum ||z_q - z||^2 == sum d_min
    }
    __syncthreads();

    // ---- gather z_q (coalesced along n) + dw atomics
    #pragma unroll
    for (int rep = 0; rep < 16; ++rep) {
        int elem = rep * 256 + tid;          // 0..4095
        int d    = elem >> 4;
        int nn   = elem & 15;
        int j    = js_s[nn];
        float zq = emb[j * D_DIM + d];
        out[OFF_ZQ + b * (D_DIM * 1024) + d * 1024 + hw0 + nn] = zq;
        float zval = ztr[d][nn];
        atomicAdd(out + OFF_EMAW + j * D_DIM + d, zval);
    }
}

// ---------------------------------------------------------------- cluster size + loss
__global__ void k_cs(const float* __restrict__ ema_cs, float* __restrict__ out) {
    __shared__ float red[K_CODES];
    int j = threadIdx.x;                     // 1024 threads
    float raw = ema_cs[j] * DECAY + (1.f - DECAY) * out[OFF_CS + j];
    red[j] = raw;
    __syncthreads();
    for (int s = 512; s > 0; s >>= 1) {
        if (j < s) red[j] += red[j + s];
        __syncthreads();
    }
    float ntot = red[0];
    float cs = (raw + EPSV) / (ntot + K_CODES * EPSV) * ntot;
    out[OFF_CS + j] = cs;
    if (j == 0) out[OFF_LOSS] = BETA * out[OFF_LOSS] / (float)(N_VEC * D_DIM);
}

// ---------------------------------------------------------------- embedding update
__global__ void k_emb(const float* __restrict__ ema_w, float* __restrict__ out) {
    int i = blockIdx.x * 256 + threadIdx.x;  // 1024 blocks -> 262144
    int j = i >> 8;
    float dw = out[OFF_EMAW + i];
    float nw = ema_w[i] * DECAY + (1.f - DECAY) * dw;
    out[OFF_EMAW + i] = nw;
    out[OFF_EMB + i]  = nw / out[OFF_CS + j];
}

// ---------------------------------------------------------------- launch
extern "C" void kernel_launch(void* const* d_in, const int* in_sizes, int n_in,
                              void* d_out, int out_size, void* d_ws, size_t ws_size,
                              hipStream_t stream) {
    const float* z      = (const float*)d_in[0];
    const float* emb    = (const float*)d_in[1];
    const float* ema_cs = (const float*)d_in[2];
    const float* ema_w  = (const float*)d_in[3];
    float* out = (float*)d_out;

    hipLaunchKernelGGL(k_init,  dim3(1024), dim3(256), 0, stream, out);
    hipLaunchKernelGGL(k_enorm, dim3(256),  dim3(256), 0, stream, emb, out);
    hipLaunchKernelGGL(k_main,  dim3(N_VEC / BM), dim3(256), 0, stream, z, emb, out);
    hipLaunchKernelGGL(k_cs,    dim3(1),    dim3(1024), 0, stream, ema_cs, out);
    hipLaunchKernelGGL(k_emb,   dim3(1024), dim3(256), 0, stream, ema_w, out);
}